// Round 14
// baseline (431.895 us; speedup 1.0000x reference)
//
#include <hip/hip_runtime.h>
#include <hip/hip_fp16.h>

#define THREADS 256
#define ELL 64       // max entries per node segment; Poisson(16) max ~40
#define RSIZE 32768  // nodes per histogram range; u8-packed counters -> 32 KB LDS
#define RS_F 16384   // nodes per fill2 range; u32 LDS cursors -> 64 KB LDS
#define NSLICE 64    // edge slices

typedef _Float16 f16x8 __attribute__((ext_vector_type(8)));
typedef float f32x4 __attribute__((ext_vector_type(4)));

// ---------- fp16 pack helpers ----------
__device__ inline uint2 pack_half4(float4 v) {
    __half2 a = __floats2half2_rn(v.x, v.y);
    __half2 b = __floats2half2_rn(v.z, v.w);
    uint2 o;
    o.x = *reinterpret_cast<unsigned int*>(&a);
    o.y = *reinterpret_cast<unsigned int*>(&b);
    return o;
}
__device__ inline float4 unpack_half4(uint2 v) {
    __half2 a = *reinterpret_cast<__half2*>(&v.x);
    __half2 b = *reinterpret_cast<__half2*>(&v.y);
    float2 f0 = __half22float2(a);
    float2 f1 = __half22float2(b);
    return make_float4(f0.x, f0.y, f1.x, f1.y);
}

// ---------- preprocessing ----------

// detect (int64 vs int32 edge layout) + self-loop at segment slot 0
__global__ void preinit_kernel(const int* __restrict__ ei, int* __restrict__ flag,
                               int* __restrict__ csr, int n) {
    int i = blockIdx.x * blockDim.x + threadIdx.x;
    if (i == 0) {
        int nz = 0;
        for (int k = 1; k < 256; k += 2) nz |= ei[k];
        *flag = (nz == 0) ? 1 : 0;  // 1 => int64 layout
    }
    if (i < n) csr[(size_t)i * ELL] = i;
}

// Fused streaming pre-pass, block-role split:
//  role A  [0, nA):       SOURCE-degree histogram (for dis)
//  role A2 [nA, 2nA):     TARGET-degree histogram (for deterministic fill)
//  role C  [2nA, +nC):    x f32 -> H16 fp16
//  role D  [.., +nD):     W fragment pack
// All roles are pure streaming: no global atomics anywhere.
// Counters are u8-packed 4-per-u32 (safe: per-slice-per-node count << 255).
__global__ __launch_bounds__(THREADS) void fused_pre_kernel(
    const int* __restrict__ ei, const int* __restrict__ flag,
    int* __restrict__ ghist, int* __restrict__ ghistT,
    const float4* __restrict__ x, uint2* __restrict__ h16,
    const float* __restrict__ w0, const float* __restrict__ w1,
    const float* __restrict__ w2, _Float16* __restrict__ wfbuf,
    int eN, int n, int nA, int nC) {
    __shared__ unsigned int lh[RSIZE / 4];   // 32 KB u8-packed counters
    const int bid = blockIdx.x;
    const int tid = threadIdx.x;

    if (bid < 2 * nA) {
        const bool tgt = (bid >= nA);
        const int b = tgt ? bid - nA : bid;
        const int g = b / NSLICE, s = b % NSLICE;
        int* gout = tgt ? ghistT : ghist;
        for (int i = tid; i < RSIZE / 4; i += THREADS) lh[i] = 0;
        __syncthreads();
        const int lo = (int)((long long)eN * s / NSLICE);
        const int hi = (int)((long long)eN * (s + 1) / NSLICE);
        const int rbase = g * RSIZE;
        const int off = tgt ? eN : 0;
        if (*flag) {
            const long long* e64 = (const long long*)ei;
            for (int idx = lo + tid; idx < hi; idx += THREADS) {
                unsigned int local = (unsigned int)((int)e64[off + idx] - rbase);
                if (local < RSIZE)
                    atomicAdd(&lh[local >> 2], 1u << ((local & 3) << 3));
            }
        } else {
            for (int idx = lo + tid; idx < hi; idx += THREADS) {
                unsigned int local = (unsigned int)(ei[off + idx] - rbase);
                if (local < RSIZE)
                    atomicAdd(&lh[local >> 2], 1u << ((local & 3) << 3));
            }
        }
        __syncthreads();
        for (int i = tid; i < RSIZE; i += THREADS) {
            int node = rbase + i;
            if (node < n)
                gout[(size_t)s * n + node] =
                    (int)((lh[i >> 2] >> ((i & 3) << 3)) & 0xFFu);
        }
    } else if (bid < 2 * nA + nC) {
        const int total = n * 32;
        for (int i = (bid - 2 * nA) * THREADS + tid; i < total; i += nC * THREADS)
            h16[i] = pack_half4(x[i]);
    } else {
        const int i = (bid - 2 * nA - nC) * THREADS + tid;   // 6144 items
        if (i < 3 * 8 * 4 * 64) {
            int lane = i & 63;
            int kt = (i >> 6) & 3;
            int nt = (i >> 8) & 7;
            int l  = i >> 11;
            const float* w = (l == 0) ? w0 : (l == 1) ? w1 : w2;
            int o  = nt * 16 + (lane & 15);
            int kb = kt * 32 + (lane >> 4) * 8;
            _Float16* dst = wfbuf + (size_t)i * 8;
#pragma unroll
            for (int j = 0; j < 8; ++j) dst[j] = (_Float16)w[o * 128 + kb + j];
        }
    }
}

// Merged: dis[i] = 1/sqrt(1 + sum_s ghist[s][i]); exclusive-scan ghistT along
// slice axis in place (counts -> starts, self-loop at 0); fill[i] = seg length.
__global__ void dis_scanT_kernel(const int* __restrict__ ghist, int* __restrict__ ghistT,
                                 float* __restrict__ dis, int* __restrict__ fill, int n) {
    int i = blockIdx.x * blockDim.x + threadIdx.x;
    if (i >= n) return;
    int deg = 1;
#pragma unroll 8
    for (int s = 0; s < NSLICE; ++s) deg += ghist[(size_t)s * n + i];
    dis[i] = 1.0f / sqrtf((float)deg);
    int running = 1;
    for (int s = 0; s < NSLICE; ++s) {
        size_t idx = (size_t)s * n + i;
        int cnt = ghistT[idx];
        ghistT[idx] = running;
        running += cnt;
    }
    fill[i] = running;
}

// Deterministic ELL fill, ZERO global atomics. Block (slice s, range g):
// LDS cursors seeded from starts[s][c]; every edge does one scattered 4B store.
__global__ __launch_bounds__(THREADS) void fill2_kernel(
    const int* __restrict__ ei, const int* __restrict__ flag,
    const int* __restrict__ starts, int* __restrict__ csr, int eN, int n) {
    __shared__ unsigned int lcur[RS_F];   // 64 KB
    const int s = blockIdx.x % NSLICE;
    const int g = blockIdx.x / NSLICE;
    const int rbase = g * RS_F;
    const int tid = threadIdx.x;
    for (int i = tid; i < RS_F; i += THREADS) {
        int node = rbase + i;
        lcur[i] = (node < n) ? (unsigned int)starts[(size_t)s * n + node] : 0u;
    }
    __syncthreads();
    const int lo = (int)((long long)eN * s / NSLICE);
    const int hi = (int)((long long)eN * (s + 1) / NSLICE);
    if (*flag) {
        const long long* e64 = (const long long*)ei;
        for (int idx = lo + tid; idx < hi; idx += THREADS) {
            int c = (int)e64[eN + idx];
            unsigned int local = (unsigned int)(c - rbase);
            if (local < RS_F) {
                int r = (int)e64[idx];
                unsigned int pos = atomicAdd(&lcur[local], 1u);  // LDS atomic only
                csr[(size_t)c * ELL + pos] = r;
            }
        }
    } else {
        for (int idx = lo + tid; idx < hi; idx += THREADS) {
            int c = ei[eN + idx];
            unsigned int local = (unsigned int)(c - rbase);
            if (local < RS_F) {
                int r = ei[idx];
                unsigned int pos = atomicAdd(&lcur[local], 1u);
                csr[(size_t)c * ELL + pos] = r;
            }
        }
    }
}

// Per node: w32[base+j] = dis[i]*dis[src_j] (sequential write) and sumw.
__global__ void sumw_kernel(const int* __restrict__ csr, const int* __restrict__ fill,
                            const float* __restrict__ dis, float* __restrict__ sumw,
                            float* __restrict__ w32, int n) {
    int i = blockIdx.x * blockDim.x + threadIdx.x;
    if (i >= n) return;
    int len = fill[i];
    const int base = i * ELL;
    const float dg = dis[i];
    float t = 0.f;
    for (int j = 0; j < len; ++j) {
        float w = dg * dis[csr[base + j]];
        w32[base + j] = w;
        t += w;
    }
    sumw[i] = t;
}

// ---------- per-layer kernels (r11-proven) ----------

// A16[i] (fp16) = sum_{seg(i)} w32[j] * h16[src_j]   (f32 accumulate)
// One wave64 per node; halves interleave edges; 4x unroll per half.
__global__ void agg_kernel(const uint2* __restrict__ h, const int* __restrict__ csr,
                           const int* __restrict__ fill, const float* __restrict__ w32,
                           uint2* __restrict__ out, int n) {
    const int wid = blockIdx.x * (blockDim.x >> 6) + (threadIdx.x >> 6);
    const int lane = threadIdx.x & 63;
    const int half = lane >> 5;
    const int l32 = lane & 31;
    if (wid >= n) return;
    const int len = fill[wid];
    const int base = wid * ELL;

    float4 a0 = make_float4(0.f, 0.f, 0.f, 0.f);
    float4 a1 = make_float4(0.f, 0.f, 0.f, 0.f);
    float4 a2 = make_float4(0.f, 0.f, 0.f, 0.f);
    float4 a3 = make_float4(0.f, 0.f, 0.f, 0.f);
    int j = half;
    for (; j + 6 < len; j += 8) {
        int u0 = csr[base + j];
        int u1 = csr[base + j + 2];
        int u2 = csr[base + j + 4];
        int u3 = csr[base + j + 6];
        float w0 = w32[base + j];
        float w1 = w32[base + j + 2];
        float w2 = w32[base + j + 4];
        float w3 = w32[base + j + 6];
        float4 v0 = unpack_half4(h[(size_t)u0 * 32 + l32]);
        float4 v1 = unpack_half4(h[(size_t)u1 * 32 + l32]);
        float4 v2 = unpack_half4(h[(size_t)u2 * 32 + l32]);
        float4 v3 = unpack_half4(h[(size_t)u3 * 32 + l32]);
        a0.x = fmaf(w0, v0.x, a0.x); a0.y = fmaf(w0, v0.y, a0.y);
        a0.z = fmaf(w0, v0.z, a0.z); a0.w = fmaf(w0, v0.w, a0.w);
        a1.x = fmaf(w1, v1.x, a1.x); a1.y = fmaf(w1, v1.y, a1.y);
        a1.z = fmaf(w1, v1.z, a1.z); a1.w = fmaf(w1, v1.w, a1.w);
        a2.x = fmaf(w2, v2.x, a2.x); a2.y = fmaf(w2, v2.y, a2.y);
        a2.z = fmaf(w2, v2.z, a2.z); a2.w = fmaf(w2, v2.w, a2.w);
        a3.x = fmaf(w3, v3.x, a3.x); a3.y = fmaf(w3, v3.y, a3.y);
        a3.z = fmaf(w3, v3.z, a3.z); a3.w = fmaf(w3, v3.w, a3.w);
    }
    for (; j < len; j += 2) {
        int u = csr[base + j];
        float w = w32[base + j];
        float4 v = unpack_half4(h[(size_t)u * 32 + l32]);
        a0.x = fmaf(w, v.x, a0.x); a0.y = fmaf(w, v.y, a0.y);
        a0.z = fmaf(w, v.z, a0.z); a0.w = fmaf(w, v.w, a0.w);
    }
    a0.x += a1.x + a2.x + a3.x;
    a0.y += a1.y + a2.y + a3.y;
    a0.z += a1.z + a2.z + a3.z;
    a0.w += a1.w + a2.w + a3.w;

    a0.x += __shfl_xor(a0.x, 32, 64);
    a0.y += __shfl_xor(a0.y, 32, 64);
    a0.z += __shfl_xor(a0.z, 32, 64);
    a0.w += __shfl_xor(a0.w, 32, 64);

    if (half == 0) {
        out[(size_t)wid * 32 + l32] = pack_half4(a0);
    }
}

// MFMA linear layer: out[r][o] = relu( sum_k A16[r][k]*W[o][k] + sumw[r]*b[o] )
template <bool OUT16>
__global__ __launch_bounds__(THREADS) void lin_mfma_kernel(
    const _Float16* __restrict__ a16, const _Float16* __restrict__ wfrag,
    const float* __restrict__ bias, const float* __restrict__ sumw,
    float* __restrict__ outf, _Float16* __restrict__ outh, int n) {
    const int lane = threadIdx.x & 63;
    const int g = lane >> 4;
    const int m15 = lane & 15;
    const int wavesPerBlock = blockDim.x >> 6;
    const int wave = blockIdx.x * wavesPerBlock + (threadIdx.x >> 6);
    const int nwaves = gridDim.x * wavesPerBlock;

    f16x8 wf[8][4];
#pragma unroll
    for (int nt = 0; nt < 8; ++nt)
#pragma unroll
        for (int kt = 0; kt < 4; ++kt)
            wf[nt][kt] = *reinterpret_cast<const f16x8*>(
                wfrag + ((size_t)((nt * 4 + kt) * 64 + lane)) * 8);

    const int ntiles = (n + 15) >> 4;
    for (int t = wave; t < ntiles; t += nwaves) {
        const int myrow = t * 16 + m15;
        const int rr = (myrow < n) ? myrow : (n - 1);
        const _Float16* arow = a16 + (size_t)rr * 128 + g * 8;
        f16x8 af[4];
#pragma unroll
        for (int kt = 0; kt < 4; ++kt)
            af[kt] = *reinterpret_cast<const f16x8*>(arow + kt * 32);

        f32x4 acc[8];
#pragma unroll
        for (int nt = 0; nt < 8; ++nt) acc[nt] = (f32x4){0.f, 0.f, 0.f, 0.f};
#pragma unroll
        for (int kt = 0; kt < 4; ++kt)
#pragma unroll
            for (int nt = 0; nt < 8; ++nt)
                acc[nt] = __builtin_amdgcn_mfma_f32_16x16x32_f16(
                    wf[nt][kt], af[kt], acc[nt], 0, 0, 0);

        if (myrow < n) {
            const float sw = sumw[myrow];
#pragma unroll
            for (int nt = 0; nt < 8; ++nt) {
                const float4 b4 = *reinterpret_cast<const float4*>(bias + nt * 16 + g * 4);
                float vx = fmaxf(acc[nt][0] + sw * b4.x, 0.f);
                float vy = fmaxf(acc[nt][1] + sw * b4.y, 0.f);
                float vz = fmaxf(acc[nt][2] + sw * b4.z, 0.f);
                float vw = fmaxf(acc[nt][3] + sw * b4.w, 0.f);
                size_t oidx = (size_t)myrow * 128 + nt * 16 + g * 4;
                if (OUT16) {
                    *reinterpret_cast<uint2*>(outh + oidx) =
                        pack_half4(make_float4(vx, vy, vz, vw));
                } else {
                    *reinterpret_cast<float4*>(outf + oidx) =
                        make_float4(vx, vy, vz, vw);
                }
            }
        }
    }
}

// ---------- host launch ----------

extern "C" void kernel_launch(void* const* d_in, const int* in_sizes, int n_in,
                              void* d_out, int out_size, void* d_ws, size_t ws_size,
                              hipStream_t stream) {
    const float* x  = (const float*)d_in[0];
    const int*   ei = (const int*)d_in[1];
    const float* Ws[3] = {(const float*)d_in[2], (const float*)d_in[4], (const float*)d_in[6]};
    const float* bs[3] = {(const float*)d_in[3], (const float*)d_in[5], (const float*)d_in[7]};
    const int n = in_sizes[0] / 128;
    const int e = in_sizes[1] / 2;

    char* ws = (char*)d_ws;
    size_t cur = 0;
    auto alloc = [&](size_t bytes) {
        void* p = ws + cur;
        cur = (cur + bytes + 255) & ~(size_t)255;
        return p;
    };
    uint2*     A16   = (uint2*)alloc((size_t)n * 128 * 2);       // agg out, fp16
    uint2*     H16   = (uint2*)alloc((size_t)n * 128 * 2);       // activations, fp16
    int*       csr   = (int*)  alloc((size_t)n * ELL * 4);       // ELL segments
    float*     w32   = (float*)alloc((size_t)n * ELL * 4);       // edge weights (f32)
    int*       ghistT= (int*)  w32;                              // overlay: dead before sumw
    int*       ghist = (int*)  alloc((size_t)NSLICE * n * 4);    // source histograms
    int*       fill  = (int*)  alloc((size_t)n * 4);
    float*     dis   = (float*)alloc((size_t)n * 4);
    float*     sumw  = (float*)alloc((size_t)n * 4);
    _Float16*  wf    = (_Float16*)alloc(3 * 8 * 4 * 64 * 8 * 2); // W fragments
    int*       flag  = (int*)  alloc(4);

    const int nr = (n + RSIZE - 1) / RSIZE;          // histogram ranges (4 @ n=100K)
    const int nA = nr * NSLICE;                      // blocks per histogram role
    const int nC = 256;                              // tofp16 blocks
    const int nD = (3 * 8 * 4 * 64 + THREADS - 1) / THREADS;
    const int nrF = (n + RS_F - 1) / RS_F;           // fill2 ranges

    preinit_kernel<<<(n + 255) / 256, 256, 0, stream>>>(ei, flag, csr, n);
    fused_pre_kernel<<<2 * nA + nC + nD, THREADS, 0, stream>>>(
        ei, flag, ghist, ghistT, (const float4*)x, H16,
        Ws[0], Ws[1], Ws[2], wf, e, n, nA, nC);
    dis_scanT_kernel<<<(n + 255) / 256, 256, 0, stream>>>(ghist, ghistT, dis, fill, n);
    fill2_kernel<<<nrF * NSLICE, THREADS, 0, stream>>>(ei, flag, ghistT, csr, e, n);
    sumw_kernel<<<(n + 255) / 256, 256, 0, stream>>>(csr, fill, dis, sumw, w32, n);

    for (int l = 0; l < 3; ++l) {
        agg_kernel<<<(n + 3) / 4, 256, 0, stream>>>(
            H16, csr, fill, w32, A16, n);
        const _Float16* wfl = wf + (size_t)l * 8 * 4 * 64 * 8;
        if (l < 2) {
            lin_mfma_kernel<true><<<512, THREADS, 0, stream>>>(
                (const _Float16*)A16, wfl, bs[l], sumw,
                nullptr, (_Float16*)H16, n);
        } else {
            lin_mfma_kernel<false><<<512, THREADS, 0, stream>>>(
                (const _Float16*)A16, wfl, bs[l], sumw,
                (float*)d_out, nullptr, n);
        }
    }
}

// Round 15
// 430.133 us; speedup vs baseline: 1.0041x; 1.0041x over previous
//
#include <hip/hip_runtime.h>
#include <hip/hip_fp16.h>

#define THREADS 256
#define ELL 64       // max entries per node segment; Poisson(16) max ~40 (< 64, and < 256 for u8)
#define RSIZE 65536  // nodes per histogram range; u8-packed counters -> 64 KB LDS
#define RS_F 65536   // nodes per fill2 range; u8-packed cursors -> 64 KB LDS
#define FTHREADS 512 // fill2 block size (8 waves for latency hiding at low block count)
#define NSLICE 64    // edge slices

typedef _Float16 f16x8 __attribute__((ext_vector_type(8)));
typedef float f32x4 __attribute__((ext_vector_type(4)));

// ---------- fp16 pack helpers ----------
__device__ inline uint2 pack_half4(float4 v) {
    __half2 a = __floats2half2_rn(v.x, v.y);
    __half2 b = __floats2half2_rn(v.z, v.w);
    uint2 o;
    o.x = *reinterpret_cast<unsigned int*>(&a);
    o.y = *reinterpret_cast<unsigned int*>(&b);
    return o;
}
__device__ inline float4 unpack_half4(uint2 v) {
    __half2 a = *reinterpret_cast<__half2*>(&v.x);
    __half2 b = *reinterpret_cast<__half2*>(&v.y);
    float2 f0 = __half22float2(a);
    float2 f1 = __half22float2(b);
    return make_float4(f0.x, f0.y, f1.x, f1.y);
}

// ---------- preprocessing ----------

// detect (int64 vs int32 edge layout) + self-loop at segment slot 0
__global__ void preinit_kernel(const int* __restrict__ ei, int* __restrict__ flag,
                               int* __restrict__ csr, int n) {
    int i = blockIdx.x * blockDim.x + threadIdx.x;
    if (i == 0) {
        int nz = 0;
        for (int k = 1; k < 256; k += 2) nz |= ei[k];
        *flag = (nz == 0) ? 1 : 0;  // 1 => int64 layout
    }
    if (i < n) csr[(size_t)i * ELL] = i;
}

// Fused streaming pre-pass, block-role split:
//  role A  [0, nA):       SOURCE-degree histogram (for dis)
//  role A2 [nA, 2nA):     TARGET-degree histogram (for deterministic fill)
//  role C  [2nA, +nC):    x f32 -> H16 fp16
//  role D  [.., +nD):     W fragment pack
// No global atomics. Counters u8-packed 4/u32 (per-slice-per-node << 255).
__global__ __launch_bounds__(THREADS) void fused_pre_kernel(
    const int* __restrict__ ei, const int* __restrict__ flag,
    int* __restrict__ ghist, int* __restrict__ ghistT,
    const float4* __restrict__ x, uint2* __restrict__ h16,
    const float* __restrict__ w0, const float* __restrict__ w1,
    const float* __restrict__ w2, _Float16* __restrict__ wfbuf,
    int eN, int n, int nA, int nC) {
    __shared__ unsigned int lh[RSIZE / 4];   // 64 KB u8-packed counters
    const int bid = blockIdx.x;
    const int tid = threadIdx.x;

    if (bid < 2 * nA) {
        const bool tgt = (bid >= nA);
        const int b = tgt ? bid - nA : bid;
        const int g = b / NSLICE, s = b % NSLICE;
        int* gout = tgt ? ghistT : ghist;
        for (int i = tid; i < RSIZE / 4; i += THREADS) lh[i] = 0;
        __syncthreads();
        const int lo = (int)((long long)eN * s / NSLICE);
        const int hi = (int)((long long)eN * (s + 1) / NSLICE);
        const int rbase = g * RSIZE;
        const int off = tgt ? eN : 0;
        if (*flag) {
            const long long* e64 = (const long long*)ei;
            for (int idx = lo + tid; idx < hi; idx += THREADS) {
                unsigned int local = (unsigned int)((int)e64[off + idx] - rbase);
                if (local < RSIZE)
                    atomicAdd(&lh[local >> 2], 1u << ((local & 3) << 3));
            }
        } else {
            for (int idx = lo + tid; idx < hi; idx += THREADS) {
                unsigned int local = (unsigned int)(ei[off + idx] - rbase);
                if (local < RSIZE)
                    atomicAdd(&lh[local >> 2], 1u << ((local & 3) << 3));
            }
        }
        __syncthreads();
        for (int i = tid; i < RSIZE; i += THREADS) {
            int node = rbase + i;
            if (node < n)
                gout[(size_t)s * n + node] =
                    (int)((lh[i >> 2] >> ((i & 3) << 3)) & 0xFFu);
        }
    } else if (bid < 2 * nA + nC) {
        const int total = n * 32;
        for (int i = (bid - 2 * nA) * THREADS + tid; i < total; i += nC * THREADS)
            h16[i] = pack_half4(x[i]);
    } else {
        const int i = (bid - 2 * nA - nC) * THREADS + tid;   // 6144 items
        if (i < 3 * 8 * 4 * 64) {
            int lane = i & 63;
            int kt = (i >> 6) & 3;
            int nt = (i >> 8) & 7;
            int l  = i >> 11;
            const float* w = (l == 0) ? w0 : (l == 1) ? w1 : w2;
            int o  = nt * 16 + (lane & 15);
            int kb = kt * 32 + (lane >> 4) * 8;
            _Float16* dst = wfbuf + (size_t)i * 8;
#pragma unroll
            for (int j = 0; j < 8; ++j) dst[j] = (_Float16)w[o * 128 + kb + j];
        }
    }
}

// Merged: dis[i] = 1/sqrt(1 + sum_s ghist[s][i]); exclusive-scan ghistT along
// slice axis in place (counts -> starts, self-loop at 0); fill[i] = seg length.
__global__ void dis_scanT_kernel(const int* __restrict__ ghist, int* __restrict__ ghistT,
                                 float* __restrict__ dis, int* __restrict__ fill, int n) {
    int i = blockIdx.x * blockDim.x + threadIdx.x;
    if (i >= n) return;
    int deg = 1;
#pragma unroll 8
    for (int s = 0; s < NSLICE; ++s) deg += ghist[(size_t)s * n + i];
    dis[i] = 1.0f / sqrtf((float)deg);
    int running = 1;
    for (int s = 0; s < NSLICE; ++s) {
        size_t idx = (size_t)s * n + i;
        int cnt = ghistT[idx];
        ghistT[idx] = running;
        running += cnt;
    }
    fill[i] = running;
}

// Deterministic ELL fill, ZERO global atomics. Block (slice s, range g):
// u8-packed LDS cursors (4/u32) seeded from starts[s][c]; safe: cursor values
// <= segment length <= 64 < 256, so no carry into the neighbor byte.
__global__ __launch_bounds__(FTHREADS) void fill2_kernel(
    const int* __restrict__ ei, const int* __restrict__ flag,
    const int* __restrict__ starts, int* __restrict__ csr, int eN, int n) {
    __shared__ unsigned int lcur[RS_F / 4];   // 64 KB u8-packed cursors
    const int s = blockIdx.x % NSLICE;
    const int g = blockIdx.x / NSLICE;
    const int rbase = g * RS_F;
    const int tid = threadIdx.x;
    const int* st = starts + (size_t)s * n;
    for (int i = tid; i < RS_F / 4; i += FTHREADS) {
        int n0 = rbase + i * 4;
        unsigned int w = 0;
#pragma unroll
        for (int k = 0; k < 4; ++k) {
            int node = n0 + k;
            unsigned int v = (node < n) ? (unsigned int)st[node] : 0u;
            w |= (v & 0xFFu) << (k * 8);
        }
        lcur[i] = w;
    }
    __syncthreads();
    const int lo = (int)((long long)eN * s / NSLICE);
    const int hi = (int)((long long)eN * (s + 1) / NSLICE);
    if (*flag) {
        const long long* e64 = (const long long*)ei;
        for (int idx = lo + tid; idx < hi; idx += FTHREADS) {
            int c = (int)e64[eN + idx];
            unsigned int local = (unsigned int)(c - rbase);
            if (local < RS_F) {
                int r = (int)e64[idx];
                unsigned int old = atomicAdd(&lcur[local >> 2], 1u << ((local & 3) << 3));
                unsigned int pos = (old >> ((local & 3) << 3)) & 0xFFu;
                csr[(size_t)c * ELL + pos] = r;
            }
        }
    } else {
        for (int idx = lo + tid; idx < hi; idx += FTHREADS) {
            int c = ei[eN + idx];
            unsigned int local = (unsigned int)(c - rbase);
            if (local < RS_F) {
                int r = ei[idx];
                unsigned int old = atomicAdd(&lcur[local >> 2], 1u << ((local & 3) << 3));
                unsigned int pos = (old >> ((local & 3) << 3)) & 0xFFu;
                csr[(size_t)c * ELL + pos] = r;
            }
        }
    }
}

// Per node: w32[base+j] = dis[i]*dis[src_j] (sequential write) and sumw.
__global__ void sumw_kernel(const int* __restrict__ csr, const int* __restrict__ fill,
                            const float* __restrict__ dis, float* __restrict__ sumw,
                            float* __restrict__ w32, int n) {
    int i = blockIdx.x * blockDim.x + threadIdx.x;
    if (i >= n) return;
    int len = fill[i];
    const int base = i * ELL;
    const float dg = dis[i];
    float t = 0.f;
    for (int j = 0; j < len; ++j) {
        float w = dg * dis[csr[base + j]];
        w32[base + j] = w;
        t += w;
    }
    sumw[i] = t;
}

// ---------- per-layer kernels (r11-proven) ----------

// A16[i] (fp16) = sum_{seg(i)} w32[j] * h16[src_j]   (f32 accumulate)
// One wave64 per node; halves interleave edges; 4x unroll per half.
__global__ void agg_kernel(const uint2* __restrict__ h, const int* __restrict__ csr,
                           const int* __restrict__ fill, const float* __restrict__ w32,
                           uint2* __restrict__ out, int n) {
    const int wid = blockIdx.x * (blockDim.x >> 6) + (threadIdx.x >> 6);
    const int lane = threadIdx.x & 63;
    const int half = lane >> 5;
    const int l32 = lane & 31;
    if (wid >= n) return;
    const int len = fill[wid];
    const int base = wid * ELL;

    float4 a0 = make_float4(0.f, 0.f, 0.f, 0.f);
    float4 a1 = make_float4(0.f, 0.f, 0.f, 0.f);
    float4 a2 = make_float4(0.f, 0.f, 0.f, 0.f);
    float4 a3 = make_float4(0.f, 0.f, 0.f, 0.f);
    int j = half;
    for (; j + 6 < len; j += 8) {
        int u0 = csr[base + j];
        int u1 = csr[base + j + 2];
        int u2 = csr[base + j + 4];
        int u3 = csr[base + j + 6];
        float w0 = w32[base + j];
        float w1 = w32[base + j + 2];
        float w2 = w32[base + j + 4];
        float w3 = w32[base + j + 6];
        float4 v0 = unpack_half4(h[(size_t)u0 * 32 + l32]);
        float4 v1 = unpack_half4(h[(size_t)u1 * 32 + l32]);
        float4 v2 = unpack_half4(h[(size_t)u2 * 32 + l32]);
        float4 v3 = unpack_half4(h[(size_t)u3 * 32 + l32]);
        a0.x = fmaf(w0, v0.x, a0.x); a0.y = fmaf(w0, v0.y, a0.y);
        a0.z = fmaf(w0, v0.z, a0.z); a0.w = fmaf(w0, v0.w, a0.w);
        a1.x = fmaf(w1, v1.x, a1.x); a1.y = fmaf(w1, v1.y, a1.y);
        a1.z = fmaf(w1, v1.z, a1.z); a1.w = fmaf(w1, v1.w, a1.w);
        a2.x = fmaf(w2, v2.x, a2.x); a2.y = fmaf(w2, v2.y, a2.y);
        a2.z = fmaf(w2, v2.z, a2.z); a2.w = fmaf(w2, v2.w, a2.w);
        a3.x = fmaf(w3, v3.x, a3.x); a3.y = fmaf(w3, v3.y, a3.y);
        a3.z = fmaf(w3, v3.z, a3.z); a3.w = fmaf(w3, v3.w, a3.w);
    }
    for (; j < len; j += 2) {
        int u = csr[base + j];
        float w = w32[base + j];
        float4 v = unpack_half4(h[(size_t)u * 32 + l32]);
        a0.x = fmaf(w, v.x, a0.x); a0.y = fmaf(w, v.y, a0.y);
        a0.z = fmaf(w, v.z, a0.z); a0.w = fmaf(w, v.w, a0.w);
    }
    a0.x += a1.x + a2.x + a3.x;
    a0.y += a1.y + a2.y + a3.y;
    a0.z += a1.z + a2.z + a3.z;
    a0.w += a1.w + a2.w + a3.w;

    a0.x += __shfl_xor(a0.x, 32, 64);
    a0.y += __shfl_xor(a0.y, 32, 64);
    a0.z += __shfl_xor(a0.z, 32, 64);
    a0.w += __shfl_xor(a0.w, 32, 64);

    if (half == 0) {
        out[(size_t)wid * 32 + l32] = pack_half4(a0);
    }
}

// MFMA linear layer: out[r][o] = relu( sum_k A16[r][k]*W[o][k] + sumw[r]*b[o] )
template <bool OUT16>
__global__ __launch_bounds__(THREADS) void lin_mfma_kernel(
    const _Float16* __restrict__ a16, const _Float16* __restrict__ wfrag,
    const float* __restrict__ bias, const float* __restrict__ sumw,
    float* __restrict__ outf, _Float16* __restrict__ outh, int n) {
    const int lane = threadIdx.x & 63;
    const int g = lane >> 4;
    const int m15 = lane & 15;
    const int wavesPerBlock = blockDim.x >> 6;
    const int wave = blockIdx.x * wavesPerBlock + (threadIdx.x >> 6);
    const int nwaves = gridDim.x * wavesPerBlock;

    f16x8 wf[8][4];
#pragma unroll
    for (int nt = 0; nt < 8; ++nt)
#pragma unroll
        for (int kt = 0; kt < 4; ++kt)
            wf[nt][kt] = *reinterpret_cast<const f16x8*>(
                wfrag + ((size_t)((nt * 4 + kt) * 64 + lane)) * 8);

    const int ntiles = (n + 15) >> 4;
    for (int t = wave; t < ntiles; t += nwaves) {
        const int myrow = t * 16 + m15;
        const int rr = (myrow < n) ? myrow : (n - 1);
        const _Float16* arow = a16 + (size_t)rr * 128 + g * 8;
        f16x8 af[4];
#pragma unroll
        for (int kt = 0; kt < 4; ++kt)
            af[kt] = *reinterpret_cast<const f16x8*>(arow + kt * 32);

        f32x4 acc[8];
#pragma unroll
        for (int nt = 0; nt < 8; ++nt) acc[nt] = (f32x4){0.f, 0.f, 0.f, 0.f};
#pragma unroll
        for (int kt = 0; kt < 4; ++kt)
#pragma unroll
            for (int nt = 0; nt < 8; ++nt)
                acc[nt] = __builtin_amdgcn_mfma_f32_16x16x32_f16(
                    wf[nt][kt], af[kt], acc[nt], 0, 0, 0);

        if (myrow < n) {
            const float sw = sumw[myrow];
#pragma unroll
            for (int nt = 0; nt < 8; ++nt) {
                const float4 b4 = *reinterpret_cast<const float4*>(bias + nt * 16 + g * 4);
                float vx = fmaxf(acc[nt][0] + sw * b4.x, 0.f);
                float vy = fmaxf(acc[nt][1] + sw * b4.y, 0.f);
                float vz = fmaxf(acc[nt][2] + sw * b4.z, 0.f);
                float vw = fmaxf(acc[nt][3] + sw * b4.w, 0.f);
                size_t oidx = (size_t)myrow * 128 + nt * 16 + g * 4;
                if (OUT16) {
                    *reinterpret_cast<uint2*>(outh + oidx) =
                        pack_half4(make_float4(vx, vy, vz, vw));
                } else {
                    *reinterpret_cast<float4*>(outf + oidx) =
                        make_float4(vx, vy, vz, vw);
                }
            }
        }
    }
}

// ---------- host launch ----------

extern "C" void kernel_launch(void* const* d_in, const int* in_sizes, int n_in,
                              void* d_out, int out_size, void* d_ws, size_t ws_size,
                              hipStream_t stream) {
    const float* x  = (const float*)d_in[0];
    const int*   ei = (const int*)d_in[1];
    const float* Ws[3] = {(const float*)d_in[2], (const float*)d_in[4], (const float*)d_in[6]};
    const float* bs[3] = {(const float*)d_in[3], (const float*)d_in[5], (const float*)d_in[7]};
    const int n = in_sizes[0] / 128;
    const int e = in_sizes[1] / 2;

    char* ws = (char*)d_ws;
    size_t cur = 0;
    auto alloc = [&](size_t bytes) {
        void* p = ws + cur;
        cur = (cur + bytes + 255) & ~(size_t)255;
        return p;
    };
    uint2*     A16   = (uint2*)alloc((size_t)n * 128 * 2);       // agg out, fp16
    uint2*     H16   = (uint2*)alloc((size_t)n * 128 * 2);       // activations, fp16
    int*       csr   = (int*)  alloc((size_t)n * ELL * 4);       // ELL segments
    float*     w32   = (float*)alloc((size_t)n * ELL * 4);       // edge weights (f32)
    int*       ghistT= (int*)  w32;                              // overlay: dead before sumw
    int*       ghist = (int*)  alloc((size_t)NSLICE * n * 4);    // source histograms
    int*       fill  = (int*)  alloc((size_t)n * 4);
    float*     dis   = (float*)alloc((size_t)n * 4);
    float*     sumw  = (float*)alloc((size_t)n * 4);
    _Float16*  wf    = (_Float16*)alloc(3 * 8 * 4 * 64 * 8 * 2); // W fragments
    int*       flag  = (int*)  alloc(4);

    const int nr = (n + RSIZE - 1) / RSIZE;          // histogram ranges (2 @ n=100K)
    const int nA = nr * NSLICE;                      // blocks per histogram role
    const int nC = 256;                              // tofp16 blocks
    const int nD = (3 * 8 * 4 * 64 + THREADS - 1) / THREADS;
    const int nrF = (n + RS_F - 1) / RS_F;           // fill2 ranges (2 @ n=100K)

    preinit_kernel<<<(n + 255) / 256, 256, 0, stream>>>(ei, flag, csr, n);
    fused_pre_kernel<<<2 * nA + nC + nD, THREADS, 0, stream>>>(
        ei, flag, ghist, ghistT, (const float4*)x, H16,
        Ws[0], Ws[1], Ws[2], wf, e, n, nA, nC);
    dis_scanT_kernel<<<(n + 255) / 256, 256, 0, stream>>>(ghist, ghistT, dis, fill, n);
    fill2_kernel<<<nrF * NSLICE, FTHREADS, 0, stream>>>(ei, flag, ghistT, csr, e, n);
    sumw_kernel<<<(n + 255) / 256, 256, 0, stream>>>(csr, fill, dis, sumw, w32, n);

    for (int l = 0; l < 3; ++l) {
        agg_kernel<<<(n + 3) / 4, 256, 0, stream>>>(
            H16, csr, fill, w32, A16, n);
        const _Float16* wfl = wf + (size_t)l * 8 * 4 * 64 * 8;
        if (l < 2) {
            lin_mfma_kernel<true><<<512, THREADS, 0, stream>>>(
                (const _Float16*)A16, wfl, bs[l], sumw,
                nullptr, (_Float16*)H16, n);
        } else {
            lin_mfma_kernel<false><<<512, THREADS, 0, stream>>>(
                (const _Float16*)A16, wfl, bs[l], sumw,
                (float*)d_out, nullptr, n);
        }
    }
}

// Round 16
// 417.329 us; speedup vs baseline: 1.0349x; 1.0307x over previous
//
#include <hip/hip_runtime.h>
#include <hip/hip_fp16.h>

#define THREADS 256
#define ELL 64       // max entries per node segment; Poisson(16) max ~40 (< 256 for u8)
#define RSIZE 32768  // nodes per histogram range; u8-packed counters -> 32 KB LDS (occupancy!)
#define RS_F 65536   // nodes per fill2 range; u8-packed cursors -> 64 KB LDS
#define FTHREADS 512 // fill2 block size (8 waves for latency hiding at low block count)
#define NSLICE 64    // edge slices

typedef _Float16 f16x8 __attribute__((ext_vector_type(8)));
typedef float f32x4 __attribute__((ext_vector_type(4)));

// ---------- fp16 pack helpers ----------
__device__ inline uint2 pack_half4(float4 v) {
    __half2 a = __floats2half2_rn(v.x, v.y);
    __half2 b = __floats2half2_rn(v.z, v.w);
    uint2 o;
    o.x = *reinterpret_cast<unsigned int*>(&a);
    o.y = *reinterpret_cast<unsigned int*>(&b);
    return o;
}
__device__ inline float4 unpack_half4(uint2 v) {
    __half2 a = *reinterpret_cast<__half2*>(&v.x);
    __half2 b = *reinterpret_cast<__half2*>(&v.y);
    float2 f0 = __half22float2(a);
    float2 f1 = __half22float2(b);
    return make_float4(f0.x, f0.y, f1.x, f1.y);
}

// ---------- preprocessing ----------

// detect (int64 vs int32 edge layout) + self-loop at segment slot 0
__global__ void preinit_kernel(const int* __restrict__ ei, int* __restrict__ flag,
                               int* __restrict__ csr, int n) {
    int i = blockIdx.x * blockDim.x + threadIdx.x;
    if (i == 0) {
        int nz = 0;
        for (int k = 1; k < 256; k += 2) nz |= ei[k];
        *flag = (nz == 0) ? 1 : 0;  // 1 => int64 layout
    }
    if (i < n) csr[(size_t)i * ELL] = i;
}

// Fused streaming pre-pass, block-role split:
//  role A  [0, nA):       SOURCE-degree histogram (for dis)
//  role A2 [nA, 2nA):     TARGET-degree histogram (for deterministic fill)
//  role C  [2nA, +nC):    x f32 -> H16 fp16
//  role D  [.., +nD):     W fragment pack
// No global atomics. Counters u8-packed 4/u32 (per-slice-per-node << 255).
// 32 KB LDS keeps 4-5 blocks/CU resident (64 KB halved occupancy, r15 regress).
__global__ __launch_bounds__(THREADS) void fused_pre_kernel(
    const int* __restrict__ ei, const int* __restrict__ flag,
    int* __restrict__ ghist, int* __restrict__ ghistT,
    const float4* __restrict__ x, uint2* __restrict__ h16,
    const float* __restrict__ w0, const float* __restrict__ w1,
    const float* __restrict__ w2, _Float16* __restrict__ wfbuf,
    int eN, int n, int nA, int nC) {
    __shared__ unsigned int lh[RSIZE / 4];   // 32 KB u8-packed counters
    const int bid = blockIdx.x;
    const int tid = threadIdx.x;

    if (bid < 2 * nA) {
        const bool tgt = (bid >= nA);
        const int b = tgt ? bid - nA : bid;
        const int g = b / NSLICE, s = b % NSLICE;
        int* gout = tgt ? ghistT : ghist;
        for (int i = tid; i < RSIZE / 4; i += THREADS) lh[i] = 0;
        __syncthreads();
        const int lo = (int)((long long)eN * s / NSLICE);
        const int hi = (int)((long long)eN * (s + 1) / NSLICE);
        const int rbase = g * RSIZE;
        const int off = tgt ? eN : 0;
        if (*flag) {
            const long long* e64 = (const long long*)ei;
            for (int idx = lo + tid; idx < hi; idx += THREADS) {
                unsigned int local = (unsigned int)((int)e64[off + idx] - rbase);
                if (local < RSIZE)
                    atomicAdd(&lh[local >> 2], 1u << ((local & 3) << 3));
            }
        } else {
            for (int idx = lo + tid; idx < hi; idx += THREADS) {
                unsigned int local = (unsigned int)(ei[off + idx] - rbase);
                if (local < RSIZE)
                    atomicAdd(&lh[local >> 2], 1u << ((local & 3) << 3));
            }
        }
        __syncthreads();
        for (int i = tid; i < RSIZE; i += THREADS) {
            int node = rbase + i;
            if (node < n)
                gout[(size_t)s * n + node] =
                    (int)((lh[i >> 2] >> ((i & 3) << 3)) & 0xFFu);
        }
    } else if (bid < 2 * nA + nC) {
        const int total = n * 32;
        for (int i = (bid - 2 * nA) * THREADS + tid; i < total; i += nC * THREADS)
            h16[i] = pack_half4(x[i]);
    } else {
        const int i = (bid - 2 * nA - nC) * THREADS + tid;   // 6144 items
        if (i < 3 * 8 * 4 * 64) {
            int lane = i & 63;
            int kt = (i >> 6) & 3;
            int nt = (i >> 8) & 7;
            int l  = i >> 11;
            const float* w = (l == 0) ? w0 : (l == 1) ? w1 : w2;
            int o  = nt * 16 + (lane & 15);
            int kb = kt * 32 + (lane >> 4) * 8;
            _Float16* dst = wfbuf + (size_t)i * 8;
#pragma unroll
            for (int j = 0; j < 8; ++j) dst[j] = (_Float16)w[o * 128 + kb + j];
        }
    }
}

// Merged: dis[i] = 1/sqrt(1 + sum_s ghist[s][i]); exclusive-scan ghistT along
// slice axis in place (counts -> starts, self-loop at 0); fill[i] = seg length.
__global__ void dis_scanT_kernel(const int* __restrict__ ghist, int* __restrict__ ghistT,
                                 float* __restrict__ dis, int* __restrict__ fill, int n) {
    int i = blockIdx.x * blockDim.x + threadIdx.x;
    if (i >= n) return;
    int deg = 1;
#pragma unroll 8
    for (int s = 0; s < NSLICE; ++s) deg += ghist[(size_t)s * n + i];
    dis[i] = 1.0f / sqrtf((float)deg);
    int running = 1;
    for (int s = 0; s < NSLICE; ++s) {
        size_t idx = (size_t)s * n + i;
        int cnt = ghistT[idx];
        ghistT[idx] = running;
        running += cnt;
    }
    fill[i] = running;
}

// Deterministic ELL fill, ZERO global atomics. Block (slice s, range g):
// u8-packed LDS cursors (4/u32) seeded from starts[s][c]; safe: cursor values
// <= segment length <= 64 < 256, so no carry into the neighbor byte.
__global__ __launch_bounds__(FTHREADS) void fill2_kernel(
    const int* __restrict__ ei, const int* __restrict__ flag,
    const int* __restrict__ starts, int* __restrict__ csr, int eN, int n) {
    __shared__ unsigned int lcur[RS_F / 4];   // 64 KB u8-packed cursors
    const int s = blockIdx.x % NSLICE;
    const int g = blockIdx.x / NSLICE;
    const int rbase = g * RS_F;
    const int tid = threadIdx.x;
    const int* st = starts + (size_t)s * n;
    for (int i = tid; i < RS_F / 4; i += FTHREADS) {
        int n0 = rbase + i * 4;
        unsigned int w = 0;
#pragma unroll
        for (int k = 0; k < 4; ++k) {
            int node = n0 + k;
            unsigned int v = (node < n) ? (unsigned int)st[node] : 0u;
            w |= (v & 0xFFu) << (k * 8);
        }
        lcur[i] = w;
    }
    __syncthreads();
    const int lo = (int)((long long)eN * s / NSLICE);
    const int hi = (int)((long long)eN * (s + 1) / NSLICE);
    if (*flag) {
        const long long* e64 = (const long long*)ei;
        for (int idx = lo + tid; idx < hi; idx += FTHREADS) {
            int c = (int)e64[eN + idx];
            unsigned int local = (unsigned int)(c - rbase);
            if (local < RS_F) {
                int r = (int)e64[idx];
                unsigned int old = atomicAdd(&lcur[local >> 2], 1u << ((local & 3) << 3));
                unsigned int pos = (old >> ((local & 3) << 3)) & 0xFFu;
                csr[(size_t)c * ELL + pos] = r;
            }
        }
    } else {
        for (int idx = lo + tid; idx < hi; idx += FTHREADS) {
            int c = ei[eN + idx];
            unsigned int local = (unsigned int)(c - rbase);
            if (local < RS_F) {
                int r = ei[idx];
                unsigned int old = atomicAdd(&lcur[local >> 2], 1u << ((local & 3) << 3));
                unsigned int pos = (old >> ((local & 3) << 3)) & 0xFFu;
                csr[(size_t)c * ELL + pos] = r;
            }
        }
    }
}

// Per node: w32[base+j] = dis[i]*dis[src_j] (sequential write) and sumw.
__global__ void sumw_kernel(const int* __restrict__ csr, const int* __restrict__ fill,
                            const float* __restrict__ dis, float* __restrict__ sumw,
                            float* __restrict__ w32, int n) {
    int i = blockIdx.x * blockDim.x + threadIdx.x;
    if (i >= n) return;
    int len = fill[i];
    const int base = i * ELL;
    const float dg = dis[i];
    float t = 0.f;
    for (int j = 0; j < len; ++j) {
        float w = dg * dis[csr[base + j]];
        w32[base + j] = w;
        t += w;
    }
    sumw[i] = t;
}

// ---------- per-layer kernels (r11-proven) ----------

// A16[i] (fp16) = sum_{seg(i)} w32[j] * h16[src_j]   (f32 accumulate)
// One wave64 per node; halves interleave edges; 4x unroll per half.
__global__ void agg_kernel(const uint2* __restrict__ h, const int* __restrict__ csr,
                           const int* __restrict__ fill, const float* __restrict__ w32,
                           uint2* __restrict__ out, int n) {
    const int wid = blockIdx.x * (blockDim.x >> 6) + (threadIdx.x >> 6);
    const int lane = threadIdx.x & 63;
    const int half = lane >> 5;
    const int l32 = lane & 31;
    if (wid >= n) return;
    const int len = fill[wid];
    const int base = wid * ELL;

    float4 a0 = make_float4(0.f, 0.f, 0.f, 0.f);
    float4 a1 = make_float4(0.f, 0.f, 0.f, 0.f);
    float4 a2 = make_float4(0.f, 0.f, 0.f, 0.f);
    float4 a3 = make_float4(0.f, 0.f, 0.f, 0.f);
    int j = half;
    for (; j + 6 < len; j += 8) {
        int u0 = csr[base + j];
        int u1 = csr[base + j + 2];
        int u2 = csr[base + j + 4];
        int u3 = csr[base + j + 6];
        float w0 = w32[base + j];
        float w1 = w32[base + j + 2];
        float w2 = w32[base + j + 4];
        float w3 = w32[base + j + 6];
        float4 v0 = unpack_half4(h[(size_t)u0 * 32 + l32]);
        float4 v1 = unpack_half4(h[(size_t)u1 * 32 + l32]);
        float4 v2 = unpack_half4(h[(size_t)u2 * 32 + l32]);
        float4 v3 = unpack_half4(h[(size_t)u3 * 32 + l32]);
        a0.x = fmaf(w0, v0.x, a0.x); a0.y = fmaf(w0, v0.y, a0.y);
        a0.z = fmaf(w0, v0.z, a0.z); a0.w = fmaf(w0, v0.w, a0.w);
        a1.x = fmaf(w1, v1.x, a1.x); a1.y = fmaf(w1, v1.y, a1.y);
        a1.z = fmaf(w1, v1.z, a1.z); a1.w = fmaf(w1, v1.w, a1.w);
        a2.x = fmaf(w2, v2.x, a2.x); a2.y = fmaf(w2, v2.y, a2.y);
        a2.z = fmaf(w2, v2.z, a2.z); a2.w = fmaf(w2, v2.w, a2.w);
        a3.x = fmaf(w3, v3.x, a3.x); a3.y = fmaf(w3, v3.y, a3.y);
        a3.z = fmaf(w3, v3.z, a3.z); a3.w = fmaf(w3, v3.w, a3.w);
    }
    for (; j < len; j += 2) {
        int u = csr[base + j];
        float w = w32[base + j];
        float4 v = unpack_half4(h[(size_t)u * 32 + l32]);
        a0.x = fmaf(w, v.x, a0.x); a0.y = fmaf(w, v.y, a0.y);
        a0.z = fmaf(w, v.z, a0.z); a0.w = fmaf(w, v.w, a0.w);
    }
    a0.x += a1.x + a2.x + a3.x;
    a0.y += a1.y + a2.y + a3.y;
    a0.z += a1.z + a2.z + a3.z;
    a0.w += a1.w + a2.w + a3.w;

    a0.x += __shfl_xor(a0.x, 32, 64);
    a0.y += __shfl_xor(a0.y, 32, 64);
    a0.z += __shfl_xor(a0.z, 32, 64);
    a0.w += __shfl_xor(a0.w, 32, 64);

    if (half == 0) {
        out[(size_t)wid * 32 + l32] = pack_half4(a0);
    }
}

// MFMA linear layer: out[r][o] = relu( sum_k A16[r][k]*W[o][k] + sumw[r]*b[o] )
template <bool OUT16>
__global__ __launch_bounds__(THREADS) void lin_mfma_kernel(
    const _Float16* __restrict__ a16, const _Float16* __restrict__ wfrag,
    const float* __restrict__ bias, const float* __restrict__ sumw,
    float* __restrict__ outf, _Float16* __restrict__ outh, int n) {
    const int lane = threadIdx.x & 63;
    const int g = lane >> 4;
    const int m15 = lane & 15;
    const int wavesPerBlock = blockDim.x >> 6;
    const int wave = blockIdx.x * wavesPerBlock + (threadIdx.x >> 6);
    const int nwaves = gridDim.x * wavesPerBlock;

    f16x8 wf[8][4];
#pragma unroll
    for (int nt = 0; nt < 8; ++nt)
#pragma unroll
        for (int kt = 0; kt < 4; ++kt)
            wf[nt][kt] = *reinterpret_cast<const f16x8*>(
                wfrag + ((size_t)((nt * 4 + kt) * 64 + lane)) * 8);

    const int ntiles = (n + 15) >> 4;
    for (int t = wave; t < ntiles; t += nwaves) {
        const int myrow = t * 16 + m15;
        const int rr = (myrow < n) ? myrow : (n - 1);
        const _Float16* arow = a16 + (size_t)rr * 128 + g * 8;
        f16x8 af[4];
#pragma unroll
        for (int kt = 0; kt < 4; ++kt)
            af[kt] = *reinterpret_cast<const f16x8*>(arow + kt * 32);

        f32x4 acc[8];
#pragma unroll
        for (int nt = 0; nt < 8; ++nt) acc[nt] = (f32x4){0.f, 0.f, 0.f, 0.f};
#pragma unroll
        for (int kt = 0; kt < 4; ++kt)
#pragma unroll
            for (int nt = 0; nt < 8; ++nt)
                acc[nt] = __builtin_amdgcn_mfma_f32_16x16x32_f16(
                    wf[nt][kt], af[kt], acc[nt], 0, 0, 0);

        if (myrow < n) {
            const float sw = sumw[myrow];
#pragma unroll
            for (int nt = 0; nt < 8; ++nt) {
                const float4 b4 = *reinterpret_cast<const float4*>(bias + nt * 16 + g * 4);
                float vx = fmaxf(acc[nt][0] + sw * b4.x, 0.f);
                float vy = fmaxf(acc[nt][1] + sw * b4.y, 0.f);
                float vz = fmaxf(acc[nt][2] + sw * b4.z, 0.f);
                float vw = fmaxf(acc[nt][3] + sw * b4.w, 0.f);
                size_t oidx = (size_t)myrow * 128 + nt * 16 + g * 4;
                if (OUT16) {
                    *reinterpret_cast<uint2*>(outh + oidx) =
                        pack_half4(make_float4(vx, vy, vz, vw));
                } else {
                    *reinterpret_cast<float4*>(outf + oidx) =
                        make_float4(vx, vy, vz, vw);
                }
            }
        }
    }
}

// ---------- host launch ----------

extern "C" void kernel_launch(void* const* d_in, const int* in_sizes, int n_in,
                              void* d_out, int out_size, void* d_ws, size_t ws_size,
                              hipStream_t stream) {
    const float* x  = (const float*)d_in[0];
    const int*   ei = (const int*)d_in[1];
    const float* Ws[3] = {(const float*)d_in[2], (const float*)d_in[4], (const float*)d_in[6]};
    const float* bs[3] = {(const float*)d_in[3], (const float*)d_in[5], (const float*)d_in[7]};
    const int n = in_sizes[0] / 128;
    const int e = in_sizes[1] / 2;

    char* ws = (char*)d_ws;
    size_t cur = 0;
    auto alloc = [&](size_t bytes) {
        void* p = ws + cur;
        cur = (cur + bytes + 255) & ~(size_t)255;
        return p;
    };
    uint2*     A16   = (uint2*)alloc((size_t)n * 128 * 2);       // agg out, fp16
    uint2*     H16   = (uint2*)alloc((size_t)n * 128 * 2);       // activations, fp16
    int*       csr   = (int*)  alloc((size_t)n * ELL * 4);       // ELL segments
    float*     w32   = (float*)alloc((size_t)n * ELL * 4);       // edge weights (f32)
    int*       ghistT= (int*)  w32;                              // overlay: dead before sumw
    int*       ghist = (int*)  alloc((size_t)NSLICE * n * 4);    // source histograms
    int*       fill  = (int*)  alloc((size_t)n * 4);
    float*     dis   = (float*)alloc((size_t)n * 4);
    float*     sumw  = (float*)alloc((size_t)n * 4);
    _Float16*  wf    = (_Float16*)alloc(3 * 8 * 4 * 64 * 8 * 2); // W fragments
    int*       flag  = (int*)  alloc(4);

    const int nr = (n + RSIZE - 1) / RSIZE;          // histogram ranges (4 @ n=100K)
    const int nA = nr * NSLICE;                      // blocks per histogram role
    const int nC = 256;                              // tofp16 blocks
    const int nD = (3 * 8 * 4 * 64 + THREADS - 1) / THREADS;
    const int nrF = (n + RS_F - 1) / RS_F;           // fill2 ranges (2 @ n=100K)

    preinit_kernel<<<(n + 255) / 256, 256, 0, stream>>>(ei, flag, csr, n);
    fused_pre_kernel<<<2 * nA + nC + nD, THREADS, 0, stream>>>(
        ei, flag, ghist, ghistT, (const float4*)x, H16,
        Ws[0], Ws[1], Ws[2], wf, e, n, nA, nC);
    dis_scanT_kernel<<<(n + 255) / 256, 256, 0, stream>>>(ghist, ghistT, dis, fill, n);
    fill2_kernel<<<nrF * NSLICE, FTHREADS, 0, stream>>>(ei, flag, ghistT, csr, e, n);
    sumw_kernel<<<(n + 255) / 256, 256, 0, stream>>>(csr, fill, dis, sumw, w32, n);

    for (int l = 0; l < 3; ++l) {
        agg_kernel<<<(n + 3) / 4, 256, 0, stream>>>(
            H16, csr, fill, w32, A16, n);
        const _Float16* wfl = wf + (size_t)l * 8 * 4 * 64 * 8;
        if (l < 2) {
            lin_mfma_kernel<true><<<512, THREADS, 0, stream>>>(
                (const _Float16*)A16, wfl, bs[l], sumw,
                nullptr, (_Float16*)H16, n);
        } else {
            lin_mfma_kernel<false><<<512, THREADS, 0, stream>>>(
                (const _Float16*)A16, wfl, bs[l], sumw,
                (float*)d_out, nullptr, n);
        }
    }
}